// Round 10
// baseline (1299.028 us; speedup 1.0000x reference)
//
#include <hip/hip_runtime.h>

// LSTM B=512,T=512,D=128,H=64,O=1. Gate order i,f,g,o.
// K1: pre[b][t][g] = x[b,t,:]@Wih0^T + bih0+bhh0  (fp32 register-tiled GEMM).
// K2: fused 2-layer recurrence. 512 blocks (1 batch) x 768 thr (12 waves = 3/EU).
//   REGALLOC MODEL (R3..R9 evidence): __launch_bounds__(N,minW) gives the
//   allocator a waves-per-EU RANGE [minW,8]; it targets the TOP (64-VGPR) and
//   sinks/spills loop-invariant weight loads to get there (R8: VGPR=72 no pins;
//   R9: identical with asm pins — pins block remat, not spills). Fix:
//   amdgpu_waves_per_eu(3,3) clamps BOTH ends -> target=3 waves/EU -> ~170-VGPR
//   budget, no sinking incentive. Per-thread weights cut to 64 floats (R3
//   empirically kept 64) -> ~115 live VGPRs, comfortable margin.
//   Geometry: sub-block m=tid/256 owns matrix m (0:Whh0,1:Wih1,2:Whh1); thread
//   (j=s>>2, qt=s&3) holds rows {g*64+j} k-slice [16qt,16qt+16). Under the
//   layer skew all three products consume OLD state -> parallel. Quad butterfly
//   (DPP xor1+xor2) -> each lane holds all 4 gate sums of unit j. Sub-2
//   publishes partials via LDS zp2; sub-0/sub-1 do cell updates in-register.
//   2 barriers/step.
// ws: 512*512*256*4 = 256 MiB fp32 pre buffer (read-only in K2).

#define TSTEPS 512

__device__ __forceinline__ float sigf(float x){ return 1.0f/(1.0f+__expf(-x)); }
__device__ __forceinline__ float tanh_fast(float x){
  float ax=fabsf(x); float e=__expf(-2.0f*ax); float r=(1.0f-e)/(1.0f+e); return copysignf(r,x);
}
// a + dpp_shuffle(b); CTRL: 0xB1=quad_perm xor1, 0x4E=quad_perm xor2
template<int CTRL>
__device__ __forceinline__ float add_dpp(float a, float b){
  return a + __int_as_float(__builtin_amdgcn_update_dpp(
      0, __float_as_int(b), CTRL, 0xF, 0xF, true));
}

// ---------------- K1: input projection GEMM (fp32 VALU) ----------------
__global__ __launch_bounds__(256) void k_inproj(
    const float* __restrict__ x, const float* __restrict__ W,
    const float* __restrict__ bih, const float* __restrict__ bhh,
    float* __restrict__ pre)
{
    __shared__ float xs[64][128];
    const int tid = threadIdx.x;
    const long row0 = (long)blockIdx.x * 64;

    const float4* __restrict__ xv = (const float4*)(x + row0 * 128);
    float4* xsv = (float4*)(&xs[0][0]);
#pragma unroll
    for (int i = 0; i < 8; ++i) xsv[tid + 256 * i] = xv[tid + 256 * i];
    __syncthreads();

    const int tx = tid & 63;
    const int ty = tid >> 6;

    float acc[16][4];
#pragma unroll
    for (int i = 0; i < 16; ++i)
#pragma unroll
        for (int j = 0; j < 4; ++j) acc[i][j] = 0.0f;

#pragma unroll 1
    for (int kc = 0; kc < 16; ++kc) {
        const int k0 = kc * 8;
        float4 w0[4], w1[4];
#pragma unroll
        for (int j = 0; j < 4; ++j) {
            const float* wr = W + (tx + 64 * j) * 128 + k0;
            w0[j] = *(const float4*)wr;
            w1[j] = *(const float4*)(wr + 4);
        }
#pragma unroll
        for (int i = 0; i < 16; ++i) {
            const int r = ty * 16 + i;
            float4 a0 = *(const float4*)(&xs[r][k0]);
            float4 a1 = *(const float4*)(&xs[r][k0 + 4]);
#pragma unroll
            for (int j = 0; j < 4; ++j) {
                float s = acc[i][j];
                s = fmaf(a0.x, w0[j].x, s); s = fmaf(a0.y, w0[j].y, s);
                s = fmaf(a0.z, w0[j].z, s); s = fmaf(a0.w, w0[j].w, s);
                s = fmaf(a1.x, w1[j].x, s); s = fmaf(a1.y, w1[j].y, s);
                s = fmaf(a1.z, w1[j].z, s); s = fmaf(a1.w, w1[j].w, s);
                acc[i][j] = s;
            }
        }
    }

    float bsum[4];
#pragma unroll
    for (int j = 0; j < 4; ++j) { const int g = tx + 64 * j; bsum[j] = bih[g] + bhh[g]; }
#pragma unroll
    for (int i = 0; i < 16; ++i) {
        const long r = row0 + ty * 16 + i;
        float* pr = pre + r * 256;
#pragma unroll
        for (int j = 0; j < 4; ++j) pr[tx + 64 * j] = acc[i][j] + bsum[j];
    }
}

// ---------------- K2: fused 2-layer recurrence + head ----------------
__global__
__attribute__((amdgpu_flat_work_group_size(768, 768)))
__attribute__((amdgpu_waves_per_eu(3, 3)))
void k_fused(
    const float* __restrict__ Whh0, const float* __restrict__ Wih1,
    const float* __restrict__ Whh1,
    const float* __restrict__ bih1, const float* __restrict__ bhh1,
    const float* __restrict__ Wfc,  const float* __restrict__ bfc,
    const float* __restrict__ pre,  float* __restrict__ out)
{
    const int tid = threadIdx.x;
    const int m   = tid >> 8;        // sub-block: 0=Whh0, 1=Wih1, 2=Whh1
    const int s   = tid & 255;
    const int j   = s >> 2;          // hidden unit 0..63
    const int qt  = s & 3;           // k-quarter (16 of 64)
    const int b   = blockIdx.x;

    __shared__ __align__(16) float h0s[2][64];
    __shared__ __align__(16) float h1s[2][64];
    __shared__ float zp2[4][64];

    // ---- 64 weight floats/thread: rows g*64+j of matrix m, k in [16qt,16qt+16)
    const float* Wm = (m == 0) ? Whh0 : (m == 1) ? Wih1 : Whh1;
    float w[4][16];
#pragma unroll
    for (int g = 0; g < 4; ++g) {
        const float4* src = (const float4*)(Wm + (g * 64 + j) * 64 + qt * 16);
#pragma unroll
        for (int i = 0; i < 4; ++i) {
            float4 v = src[i];
            w[g][4*i+0] = v.x; w[g][4*i+1] = v.y; w[g][4*i+2] = v.z; w[g][4*i+3] = v.w;
        }
    }
    float bias1v[4];
#pragma unroll
    for (int g = 0; g < 4; ++g) bias1v[g] = bih1[g * 64 + j] + bhh1[g * 64 + j];

    const float* __restrict__ pb = pre + (size_t)b * TSTEPS * 256;
    float pc[4];
#pragma unroll
    for (int g = 0; g < 4; ++g) pc[g] = pb[g * 64 + j];   // t=0 (used by m==0)

    if (tid < 64) { h0s[0][tid] = 0.0f; h1s[0][tid] = 0.0f; }
    float cst = 0.0f;   // c-state: (m==0,qt==0) -> c0[j]; (m==1,qt==0) -> c1[j]
    int p = 0;
    __syncthreads();

#pragma unroll 1
    for (int n = 0; n <= TSTEPS; ++n) {
        // h slice for my matrix (old state, parity p): m<2 -> h0, m==2 -> h1
        const float* hsrc = (m == 2) ? &h1s[p][qt * 16] : &h0s[p][qt * 16];
        float hv[16];
#pragma unroll
        for (int i = 0; i < 4; ++i) {
            float4 v = *(const float4*)(hsrc + 4 * i);
            hv[4*i+0] = v.x; hv[4*i+1] = v.y; hv[4*i+2] = v.z; hv[4*i+3] = v.w;
        }

        // prefetch next pre0 (sub-0 only)
        float pn_[4] = {0, 0, 0, 0};
        const int tn = (n < TSTEPS - 1) ? n + 1 : 0;
        if (m == 0) {
#pragma unroll
            for (int g = 0; g < 4; ++g) pn_[g] = pb[tn * 256 + g * 64 + j];
        }

        // ---- dots: 4 gates x 16 k, 4 independent sub-chains each ----
        float z[4];
#pragma unroll
        for (int g = 0; g < 4; ++g) {
            float t0 = 0, t1 = 0, t2 = 0, t3 = 0;
#pragma unroll
            for (int k = 0; k < 4; ++k) {
                t0 = fmaf(w[g][k],      hv[k],      t0);
                t1 = fmaf(w[g][4 + k],  hv[4 + k],  t1);
                t2 = fmaf(w[g][8 + k],  hv[8 + k],  t2);
                t3 = fmaf(w[g][12 + k], hv[12 + k], t3);
            }
            float sum = (t0 + t1) + (t2 + t3);
            sum = add_dpp<0xB1>(sum, sum);   // quad xor1
            sum = add_dpp<0x4E>(sum, sum);   // quad xor2 -> full 64-k sum
            z[g] = sum;
        }

        // sub-2 publishes Whh1.h1 partials
        if (m == 2 && qt == 0) {
#pragma unroll
            for (int g = 0; g < 4; ++g) zp2[g][j] = z[g];
        }
        __syncthreads();   // zp2 visible

        // ---- cell updates (qt==0 lanes) ----
        if (qt == 0) {
            if (m == 0) {
                if (n < TSTEPS) {
                    float z0 = z[0] + pc[0], z1 = z[1] + pc[1];
                    float z2 = z[2] + pc[2], z3 = z[3] + pc[3];
                    float i_ = sigf(z0), f_ = sigf(z1), g_ = tanh_fast(z2), o_ = sigf(z3);
                    cst = fmaf(f_, cst, i_ * g_);
                    h0s[p ^ 1][j] = o_ * tanh_fast(cst);
                }
            } else if (m == 1) {
                if (n >= 1) {
                    float z0 = z[0] + bias1v[0] + zp2[0][j];
                    float z1 = z[1] + bias1v[1] + zp2[1][j];
                    float z2 = z[2] + bias1v[2] + zp2[2][j];
                    float z3 = z[3] + bias1v[3] + zp2[3][j];
                    float i_ = sigf(z0), f_ = sigf(z1), g_ = tanh_fast(z2), o_ = sigf(z3);
                    cst = fmaf(f_, cst, i_ * g_);
                    h1s[p ^ 1][j] = o_ * tanh_fast(cst);
                }
            }
        }
        __syncthreads();   // new h visible
        p ^= 1;
        if (m == 0) {
#pragma unroll
            for (int g = 0; g < 4; ++g) pc[g] = pn_[g];
        }
    }

    // ---- head: out[b] = h1_{T-1} . Wfc + bfc (wave 0) ----
    if (tid < 64) {
        float v = h1s[p][tid] * Wfc[tid];
#pragma unroll
        for (int off = 32; off > 0; off >>= 1) v += __shfl_down(v, off);
        if (tid == 0) out[b] = v + bfc[0];
    }
}

extern "C" void kernel_launch(void* const* d_in, const int* in_sizes, int n_in,
                              void* d_out, int out_size, void* d_ws, size_t ws_size,
                              hipStream_t stream)
{
    const float* x    = (const float*)d_in[0];
    const float* Wih0 = (const float*)d_in[1];
    const float* Whh0 = (const float*)d_in[2];
    const float* bih0 = (const float*)d_in[3];
    const float* bhh0 = (const float*)d_in[4];
    const float* Wih1 = (const float*)d_in[5];
    const float* Whh1 = (const float*)d_in[6];
    const float* bih1 = (const float*)d_in[7];
    const float* bhh1 = (const float*)d_in[8];
    const float* Wfc  = (const float*)d_in[9];
    const float* bfc  = (const float*)d_in[10];
    float* out = (float*)d_out;
    float* pre = (float*)d_ws;  // [B][T][256] fp32 = 256 MiB

    k_inproj<<<4096, 256, 0, stream>>>(x, Wih0, bih0, bhh0, pre);
    k_fused<<<512, 768, 0, stream>>>(Whh0, Wih1, Whh1, bih1, bhh1, Wfc, bfc, pre, out);
}